// Round 1
// baseline (2027.597 us; speedup 1.0000x reference)
//
#include <hip/hip_runtime.h>
#include <hip/hip_bf16.h>
#include <math.h>

// Problem constants
#define DIMK   1024
#define SEQ    512
#define NE     8
#define DFF    2730
#define DFF2   5460
#define VOCAB  32000
#define NPAIR  1024      // SEQ * K(=2)
#define KPADD  2752      // DFF padded to %32 for down-proj K loop

typedef __attribute__((ext_vector_type(4))) float  f32x4;
typedef __attribute__((ext_vector_type(8))) __bf16 bf16x8;   // MFMA operand type (LLVM gfx950: V8y)
typedef __attribute__((ext_vector_type(8))) short  s16x8;
typedef unsigned int u32;

// ---------- ws layout (bytes) ----------
// 0        pair_expert  int[1024]
// 4096     pair_gate    float[1024]
// 8192     cnt int[8] | 8224 off int[8] | 8256 cur int[8]
// 8288     grouped_rows int[1024]
// 16384    x_bf16   [512][1024]  bf16   (1 MB)
// 1064960  h_full   [1024][5460] fp32   (22.4 MB)
// 23429120 h_act    [1024][2752] bf16   (5.6 MB, zero-padded K tail)
// 29065216 h2       [1024][1024] bf16   (2 MB)
// 31162368 logits   [1024][32000] bf16  (65.5 MB)
// total ~96.7 MB

__device__ __forceinline__ short f2bf(float f) {
    u32 u = __builtin_bit_cast(u32, f);
    u32 r = u + 0x7fffu + ((u >> 16) & 1u);   // RNE
    return (short)(r >> 16);
}
__device__ __forceinline__ float bf2f(short b) {
    u32 u = ((u32)(unsigned short)b) << 16;
    return __builtin_bit_cast(float, u);
}

// ---------------- x -> bf16 ----------------
__global__ __launch_bounds__(256) void k_cvtx(const float* __restrict__ x, short* __restrict__ xb) {
    int i = (blockIdx.x * 256 + threadIdx.x) * 4;
    float4 v = *(const float4*)(x + i);
    short4 o;
    o.x = f2bf(v.x); o.y = f2bf(v.y); o.z = f2bf(v.z); o.w = f2bf(v.w);
    *(short4*)(xb + i) = o;
}

// ---------------- router: fp32 scores, top-2, gate logp ----------------
__global__ __launch_bounds__(256) void k_router(const float* __restrict__ x, const float* __restrict__ Wr,
                                                int* __restrict__ pair_e, float* __restrict__ pair_g,
                                                int* __restrict__ cnt) {
    int wave = threadIdx.x >> 6, lane = threadIdx.x & 63;
    int t = blockIdx.x * 4 + wave;                 // token
    float p[NE];
#pragma unroll
    for (int e = 0; e < NE; ++e) p[e] = 0.f;
    const float* xr = x + t * DIMK;
#pragma unroll
    for (int it = 0; it < DIMK / 64; ++it) {
        int k = lane + it * 64;
        float xv = xr[k];
#pragma unroll
        for (int e = 0; e < NE; ++e) p[e] += xv * Wr[e * DIMK + k];
    }
#pragma unroll
    for (int e = 0; e < NE; ++e) {
#pragma unroll
        for (int off = 32; off >= 1; off >>= 1) p[e] += __shfl_xor(p[e], off);
    }
    if (lane == 0) {
        int i0 = 0; float s0 = p[0];
        for (int e = 1; e < NE; ++e) if (p[e] > s0) { s0 = p[e]; i0 = e; }   // ties -> lowest idx (lax.top_k)
        int i1 = -1; float s1 = -INFINITY;
        for (int e = 0; e < NE; ++e) { if (e == i0) continue; if (p[e] > s1) { s1 = p[e]; i1 = e; } }
        float lse = s0 + log1pf(expf(s1 - s0));
        pair_e[2 * t]     = i0; pair_e[2 * t + 1] = i1;
        pair_g[2 * t]     = s0 - lse;
        pair_g[2 * t + 1] = s1 - lse;
        atomicAdd(&cnt[i0], 1); atomicAdd(&cnt[i1], 1);
    }
}

// ---------------- group pairs by expert ----------------
__global__ __launch_bounds__(1024) void k_group(const int* __restrict__ pair_e, const int* __restrict__ cnt,
                                                int* __restrict__ off, int* __restrict__ cur,
                                                int* __restrict__ grouped) {
    if (threadIdx.x == 0) {
        int r = 0;
        for (int e = 0; e < NE; ++e) { off[e] = r; r += cnt[e]; }
    }
    __syncthreads();
    int j = threadIdx.x;                       // pair index 0..1023
    int e = pair_e[j];
    int pos = off[e] + atomicAdd(&cur[e], 1);
    grouped[pos] = j;
}

// ---------------- grouped GEMM: C[row, n] = A[row,:] . W[e][n,:]  (bf16 MFMA) ----------------
// EPI 0: h_full fp32 = acc + bup[e][col]
// EPI 1: h2 bf16     = acc + x[token][col]   (residual)
// EPI 2: logits bf16 = acc
template <int EPI, int NOUT, int WSTR, int KACT, int KP, int ASTR, bool ATOK, bool ALIGNED>
__global__ __launch_bounds__(256) void k_gemm(const short* __restrict__ A, const float* __restrict__ W,
                                              const int* __restrict__ cnt, const int* __restrict__ off,
                                              const int* __restrict__ grouped,
                                              float* __restrict__ out_f, short* __restrict__ out_b,
                                              const float* __restrict__ aux) {
    constexpr int BM = 256, BN = 64, BK = 32;
    __shared__ short Als[BM * BK];   // 16 KB, row-major [m][k]
    __shared__ short Bls[BN * BK];   // 4 KB,  row-major [n][k]
    const int e = blockIdx.y;
    const int rows = cnt[e];
    if (rows == 0) return;
    const int* rl = grouped + off[e];
    const int n0 = blockIdx.x * BN;
    const int tid = threadIdx.x, lane = tid & 63, wave = tid >> 6;
    const float* We = W + (size_t)e * NOUT * WSTR;

    // B staging assignment: thread -> (row n = tid>>2, k-chunk (tid&3)*8)
    const int bn = tid >> 2;
    int wrow = n0 + bn; if (wrow >= NOUT) wrow = NOUT - 1;    // clamp (cols masked at store)
    const float* bgp = We + (size_t)wrow * WSTR + (tid & 3) * 8;
    short* bl = &Bls[bn * BK + (tid & 3) * 8];

    for (int m0 = 0; m0 < rows; m0 += BM) {
        f32x4 acc[4][4] = {};
        // A gather pointers: wave issues 4 global_load_lds, each covers 16 rows (lane>>2) x 16B (lane&3)
        const short* agp[4];
#pragma unroll
        for (int q = 0; q < 4; ++q) {
            int rt = (wave * 4 + q) * 16 + (lane >> 2);
            int idx = m0 + rt; if (idx >= rows) idx = rows - 1;   // clamp; rows masked at store
            int pr = rl[idx];
            int ar = ATOK ? (pr >> 1) : pr;
            agp[q] = A + (size_t)ar * ASTR + (lane & 3) * 8;
        }

        for (int k0 = 0; k0 < KP; k0 += BK) {
            __syncthreads();
#pragma unroll
            for (int q = 0; q < 4; ++q) {
                __builtin_amdgcn_global_load_lds(
                    (const __attribute__((address_space(1))) u32*)(agp[q] + k0),
                    (__attribute__((address_space(3))) u32*)(&Als[(wave * 4 + q) * 16 * BK]),
                    16, 0, 0);
            }
            float bv[8];
            if (ALIGNED) {
                float4 v0 = *(const float4*)(bgp + k0);
                float4 v1 = *(const float4*)(bgp + k0 + 4);
                bv[0] = v0.x; bv[1] = v0.y; bv[2] = v0.z; bv[3] = v0.w;
                bv[4] = v1.x; bv[5] = v1.y; bv[6] = v1.z; bv[7] = v1.w;
            } else {
                int kb = k0 + (tid & 3) * 8;
#pragma unroll
                for (int i = 0; i < 8; ++i) bv[i] = (kb + i < KACT) ? bgp[k0 + i] : 0.f;
            }
            s16x8 bw;
#pragma unroll
            for (int i = 0; i < 8; ++i) bw[i] = f2bf(bv[i]);
            *(s16x8*)bl = bw;
            __syncthreads();

            const int mr = lane & 15, kh = (lane >> 4) * 8;
            bf16x8 aF[4], bF[4];
#pragma unroll
            for (int i = 0; i < 4; ++i) aF[i] = *(const bf16x8*)&Als[(wave * 64 + i * 16 + mr) * BK + kh];
#pragma unroll
            for (int j = 0; j < 4; ++j) bF[j] = *(const bf16x8*)&Bls[(j * 16 + mr) * BK + kh];
#pragma unroll
            for (int i = 0; i < 4; ++i)
#pragma unroll
                for (int j = 0; j < 4; ++j)
                    acc[i][j] = __builtin_amdgcn_mfma_f32_16x16x32_bf16(aF[i], bF[j], acc[i][j], 0, 0, 0);
        }

        // epilogue: D row = (lane>>4)*4 + r, col = lane&15 (m89/m91-verified mapping)
#pragma unroll
        for (int i = 0; i < 4; ++i) {
#pragma unroll
            for (int r = 0; r < 4; ++r) {
                int grow = wave * 64 + i * 16 + (lane >> 4) * 4 + r;
                int idx = m0 + grow;
                if (idx < rows) {
                    int pr = rl[idx];
#pragma unroll
                    for (int j = 0; j < 4; ++j) {
                        int col = n0 + j * 16 + (lane & 15);
                        if (col < NOUT) {
                            float v = acc[i][j][r];
                            if (EPI == 0)      out_f[(size_t)pr * NOUT + col] = v + aux[(size_t)e * NOUT + col];
                            else if (EPI == 1) out_b[(size_t)pr * DIMK + col] = f2bf(v + aux[(size_t)(pr >> 1) * DIMK + col]);
                            else               out_b[(size_t)pr * (size_t)NOUT + col] = f2bf(v);
                        }
                    }
                }
            }
        }
    }
}

// ---------------- SwiGLU: h = up * gelu_exact(gate), write zero-padded bf16 ----------------
__global__ __launch_bounds__(256) void k_swiglu(const float* __restrict__ hf, short* __restrict__ ha) {
    int row = blockIdx.x;
    const float* hr = hf + (size_t)row * DFF2;
    short* orow = ha + (size_t)row * KPADD;
    for (int f = threadIdx.x; f < KPADD; f += 256) {
        short o = 0;
        if (f < DFF) {
            float up = hr[f], g = hr[DFF + f];
            float gel = 0.5f * g * (1.f + erff(g * 0.70710678118654752f));
            o = f2bf(up * gel);
        }
        orow[f] = o;
    }
}

// ---------------- per-token: row-lse over vocab then gated logaddexp of the 2 experts ----------------
__global__ __launch_bounds__(256) void k_combine(const short* __restrict__ logits,
                                                 const float* __restrict__ pair_g, float* __restrict__ out) {
    int t = blockIdx.x;
    const short* l0 = logits + (size_t)(2 * t) * VOCAB;
    const short* l1 = l0 + VOCAB;
    int lane = threadIdx.x & 63, wave = threadIdx.x >> 6;
    float m0 = -INFINITY, s0 = 0.f, m1 = -INFINITY, s1 = 0.f;
    for (int v = threadIdx.x; v < VOCAB; v += 256) {
        float a = bf2f(l0[v]);
        if (a > m0) { s0 = s0 * expf(m0 - a) + 1.f; m0 = a; } else s0 += expf(a - m0);
        float b = bf2f(l1[v]);
        if (b > m1) { s1 = s1 * expf(m1 - b) + 1.f; m1 = b; } else s1 += expf(b - m1);
    }
#pragma unroll
    for (int off = 32; off >= 1; off >>= 1) {
        float om = __shfl_xor(m0, off), os = __shfl_xor(s0, off);
        if (om > m0) { s0 = s0 * expf(m0 - om) + os; m0 = om; } else s0 += os * expf(om - m0);
        om = __shfl_xor(m1, off); os = __shfl_xor(s1, off);
        if (om > m1) { s1 = s1 * expf(m1 - om) + os; m1 = om; } else s1 += os * expf(om - m1);
    }
    __shared__ float red[4][4];
    __shared__ float cc[2];
    if (lane == 0) { red[wave][0] = m0; red[wave][1] = s0; red[wave][2] = m1; red[wave][3] = s1; }
    __syncthreads();
    if (threadIdx.x == 0) {
        float M0 = -INFINITY, S0 = 0.f, M1 = -INFINITY, S1 = 0.f;
        for (int w = 0; w < 4; ++w) {
            float am = red[w][0], as = red[w][1];
            if (am > M0) { S0 = S0 * expf(M0 - am) + as; M0 = am; } else S0 += as * expf(am - M0);
            am = red[w][2]; as = red[w][3];
            if (am > M1) { S1 = S1 * expf(M1 - am) + as; M1 = am; } else S1 += as * expf(am - M1);
        }
        float lse0 = M0 + logf(S0), lse1 = M1 + logf(S1);
        cc[0] = pair_g[2 * t]     - lse0;
        cc[1] = pair_g[2 * t + 1] - lse1;
    }
    __syncthreads();
    float c0 = cc[0], c1 = cc[1];
    float* orow = out + (size_t)t * VOCAB;
    for (int v = threadIdx.x; v < VOCAB; v += 256) {
        float a = bf2f(l0[v]) + c0, b = bf2f(l1[v]) + c1;
        float mm = fmaxf(a, b), mn = fminf(a, b);
        orow[v] = mm + log1pf(expf(mn - mm));
    }
}

extern "C" void kernel_launch(void* const* d_in, const int* in_sizes, int n_in,
                              void* d_out, int out_size, void* d_ws, size_t ws_size,
                              hipStream_t stream) {
    const float* x     = (const float*)d_in[0];
    const float* Wr    = (const float*)d_in[1];
    const float* Wup   = (const float*)d_in[2];
    const float* bup   = (const float*)d_in[3];
    const float* Wdown = (const float*)d_in[4];
    const float* Wproj = (const float*)d_in[5];
    float* out = (float*)d_out;
    char* ws = (char*)d_ws;
    int*   pair_e  = (int*)(ws + 0);
    float* pair_g  = (float*)(ws + 4096);
    int*   cnt     = (int*)(ws + 8192);
    int*   offp    = (int*)(ws + 8224);
    int*   cur     = (int*)(ws + 8256);
    int*   grouped = (int*)(ws + 8288);
    short* xb      = (short*)(ws + 16384);
    float* hfull   = (float*)(ws + 1064960);
    short* hact    = (short*)(ws + 23429120);
    short* h2      = (short*)(ws + 29065216);
    short* logits  = (short*)(ws + 31162368);

    hipMemsetAsync(cnt, 0, 96, stream);                      // cnt/off/cur
    k_cvtx<<<512, 256, 0, stream>>>(x, xb);
    k_router<<<128, 256, 0, stream>>>(x, Wr, pair_e, pair_g, cnt);
    k_group<<<1, 1024, 0, stream>>>(pair_e, cnt, offp, cur, grouped);
    // up-proj: N=5460, K=1024
    k_gemm<0, DFF2, DIMK, DIMK, DIMK, DIMK, true, true><<<dim3(86, 8), 256, 0, stream>>>(
        xb, Wup, cnt, offp, grouped, hfull, nullptr, bup);
    k_swiglu<<<1024, 256, 0, stream>>>(hfull, hact);
    // down-proj: N=1024, K=2730 (padded 2752), unaligned weight rows
    k_gemm<1, DIMK, DFF, DFF, KPADD, KPADD, false, false><<<dim3(16, 8), 256, 0, stream>>>(
        hact, Wdown, cnt, offp, grouped, nullptr, h2, x);
    // vocab proj: N=32000, K=1024
    k_gemm<2, VOCAB, DIMK, DIMK, DIMK, DIMK, false, true><<<dim3(500, 8), 256, 0, stream>>>(
        h2, Wproj, cnt, offp, grouped, nullptr, logits, nullptr);
    k_combine<<<512, 256, 0, stream>>>(logits, pair_g, out);
}